// Round 3
// baseline (63.094 us; speedup 1.0000x reference)
//
#include <hip/hip_runtime.h>

#define CH 64
#define NN 56
#define XS (NN*NN)        // 3136 floats per channel image
#define RPB 7             // output rows per block
#define TR  8             // t4 row slots (RPB + 1)

// out[i,m,l] = g1[i,0]*t4[i,(m-1)%56,l] + g1[i,1]*t4[i,(m-2)%56,l]
// t4[i,n,l]  = sum_j sum_k g2[i,j,k] * x[j,n,l+k-1]   (zero-pad in l)
//
// Block = (pair of output channels {i0,i0+1}, group of 7 output rows).
// 256 threads = 8 row-slots x 32 lanes; each lane owns a float2 of columns
// (28 active lanes cover 56 cols). One x load + 2 shuffles feed the FMAs of
// BOTH output channels (12 MAC per j per lane) -> halves x traffic and
// amortizes shuffle/mask overhead. Weight reads are thread-uniform and
// contiguous across j -> scalar s_load_dwordx batches.
__global__ __launch_bounds__(256) void fused_shift_conv3(
    const float* __restrict__ x,
    const float* __restrict__ g1,
    const float* __restrict__ g2,
    float* __restrict__ out)
{
    __shared__ float t4s[2][TR][NN];

    const int ip = blockIdx.x >> 3;    // channel pair 0..31
    const int g  = blockIdx.x & 7;     // row group 0..7
    const int i0 = ip * 2;
    const int r0 = g * RPB;

    const int tid = threadIdx.x;
    const int wv  = tid >> 5;          // row slot 0..7
    const int lr  = tid & 31;          // lane within row
    const int n   = (r0 - 2 + wv + NN) % NN;   // t4 row (wraps mod 56)

    const bool act = (lr < 28);
    const int  c   = (act ? lr : 27) * 2;      // clamped column base (even)

    const bool mL = (lr == 0);    // col 0 has no left tap
    const bool mH = (lr == 27);   // col 55 has no right tap

    const float* xp  = x + n * NN + c;
    const float* wpa = g2 + i0 * (CH * 3);     // uniform -> scalar loads
    const float* wpb = wpa + (CH * 3);

    float a0x = 0.f, a0y = 0.f, a1x = 0.f, a1y = 0.f;

    #pragma unroll 8
    for (int j = 0; j < CH; ++j) {
        float2 v = *(const float2*)(xp + j * XS);
        float xl = __shfl_up(v.y, 1);          // x[c-1] from lane-1
        float xh = __shfl_down(v.x, 1);        // x[c+2] from lane+1
        xl = mL ? 0.f : xl;
        xh = mH ? 0.f : xh;

        const float wa0 = wpa[3*j+0], wa1 = wpa[3*j+1], wa2 = wpa[3*j+2];
        const float wb0 = wpb[3*j+0], wb1 = wpb[3*j+1], wb2 = wpb[3*j+2];

        a0x = fmaf(xl,  wa0, a0x);
        a0x = fmaf(v.x, wa1, a0x);
        a0x = fmaf(v.y, wa2, a0x);
        a0y = fmaf(v.x, wa0, a0y);
        a0y = fmaf(v.y, wa1, a0y);
        a0y = fmaf(xh,  wa2, a0y);

        a1x = fmaf(xl,  wb0, a1x);
        a1x = fmaf(v.x, wb1, a1x);
        a1x = fmaf(v.y, wb2, a1x);
        a1y = fmaf(v.x, wb0, a1y);
        a1y = fmaf(v.y, wb1, a1y);
        a1y = fmaf(xh,  wb2, a1y);
    }

    if (act) {
        *(float2*)&t4s[0][wv][c] = make_float2(a0x, a0y);
        *(float2*)&t4s[1][wv][c] = make_float2(a1x, a1y);
    }
    __syncthreads();

    if (wv < RPB && act) {
        const int m = r0 + wv;
        const float b00 = g1[i0*2+0], b01 = g1[i0*2+1];
        const float b10 = g1[i0*2+2], b11 = g1[i0*2+3];

        const float2 tA0 = *(const float2*)&t4s[0][wv+1][c];
        const float2 tB0 = *(const float2*)&t4s[0][wv][c];
        const float2 tA1 = *(const float2*)&t4s[1][wv+1][c];
        const float2 tB1 = *(const float2*)&t4s[1][wv][c];

        float2 o0, o1;
        o0.x = fmaf(b00, tA0.x, b01 * tB0.x);
        o0.y = fmaf(b00, tA0.y, b01 * tB0.y);
        o1.x = fmaf(b10, tA1.x, b11 * tB1.x);
        o1.y = fmaf(b10, tA1.y, b11 * tB1.y);

        *(float2*)&out[i0*XS + m*NN + c]     = o0;
        *(float2*)&out[(i0+1)*XS + m*NN + c] = o1;
    }
}

extern "C" void kernel_launch(void* const* d_in, const int* in_sizes, int n_in,
                              void* d_out, int out_size, void* d_ws, size_t ws_size,
                              hipStream_t stream) {
    const float* x  = (const float*)d_in[0];
    const float* w1 = (const float*)d_in[1];
    const float* w2 = (const float*)d_in[2];
    float* out      = (float*)d_out;

    dim3 grid(32 * 8);     // 32 channel-pairs x 8 row-groups = 256 blocks (1/CU)
    dim3 block(256);       // 8 row-slots x 32 lanes
    hipLaunchKernelGGL(fused_shift_conv3, grid, block, 0, stream, x, w1, w2, out);
}